// Round 3
// baseline (20531.036 us; speedup 1.0000x reference)
//
#include <hip/hip_runtime.h>
#include <climits>
#include <cmath>

// Greedy autoregressive LSTM decoder, persistent cooperative kernel, v3.
// 256 blocks x 1024 threads (16 waves/CU), flag grid barrier (2/step).
// Logits: fp16 W_lin (converted per-launch into d_ws) + v_dot2_f32_f16,
// with top-3 tracking and fp32 recompute of candidates on close calls
// (m0-m1 < THR) so the greedy argmax matches the fp32 reference.
// Gates/h path stays fully fp32 (h exactness protects the token chain).

#define NBLK 256
#define NTHR 1024
#define WPB  16
#define Bb 16
#define Hh 1024
#define Vv 32000
#define Tt 128
#define P32 1028                  // fp32 LDS pitch (floats)
#define P16 1032                  // fp16 LDS pitch (halfs)
#define THR 0.01f

typedef float v4f __attribute__((ext_vector_type(4)));
typedef _Float16 h2v __attribute__((ext_vector_type(2)));
typedef _Float16 h8v __attribute__((ext_vector_type(8)));

#define NEG_INF (-__builtin_inff())

__device__ __forceinline__ float dot4f(v4f a, v4f b, float acc) {
  return fmaf(a.x, b.x, fmaf(a.y, b.y, fmaf(a.z, b.z, fmaf(a.w, b.w, acc))));
}

__device__ __forceinline__ float dot8h(h8v x, h8v y, float acc) {
#if defined(__has_builtin)
#if __has_builtin(__builtin_amdgcn_fdot2)
  h2v x0 = {x[0], x[1]}, x1 = {x[2], x[3]}, x2 = {x[4], x[5]}, x3 = {x[6], x[7]};
  h2v y0 = {y[0], y[1]}, y1 = {y[2], y[3]}, y2 = {y[4], y[5]}, y3 = {y[6], y[7]};
  acc = __builtin_amdgcn_fdot2(x0, y0, acc, false);
  acc = __builtin_amdgcn_fdot2(x1, y1, acc, false);
  acc = __builtin_amdgcn_fdot2(x2, y2, acc, false);
  acc = __builtin_amdgcn_fdot2(x3, y3, acc, false);
  return acc;
#else
#pragma unroll
  for (int k = 0; k < 8; ++k) acc = fmaf((float)x[k], (float)y[k], acc);
  return acc;
#endif
#else
#pragma unroll
  for (int k = 0; k < 8; ++k) acc = fmaf((float)x[k], (float)y[k], acc);
  return acc;
#endif
}

__device__ __forceinline__ bool better(float x, int xi, float y, int yi) {
  return (x > y) || (x == y && xi < yi);    // np.argmax: first index wins ties
}
__device__ __forceinline__ void ins3(float& m0, float& m1, float& m2,
                                     int& i0, int& i1, int& i2, float x, int xi) {
  if (better(x, xi, m0, i0))      { m2 = m1; i2 = i1; m1 = m0; i1 = i0; m0 = x; i0 = xi; }
  else if (better(x, xi, m1, i1)) { m2 = m1; i2 = i1; m1 = x; i1 = xi; }
  else if (better(x, xi, m2, i2)) { m2 = x; i2 = xi; }
}
__device__ __forceinline__ void lse_merge(float& M, float& S, float m2, float s2) {
  float nM = fmaxf(M, m2);
  float a = (M  > NEG_INF) ? S  * __expf(M  - nM) : 0.f;
  float b = (m2 > NEG_INF) ? s2 * __expf(m2 - nM) : 0.f;
  M = nM; S = a + b;
}

// Flag-based grid barrier (no same-address RMW contention). Proven in R2.
__device__ __forceinline__ void grid_barrier(int* flags, int* gen, int epoch) {
  __syncthreads();
  if (threadIdx.x == 0) {
    __hip_atomic_store(&flags[blockIdx.x * 16], epoch,
                       __ATOMIC_RELEASE, __HIP_MEMORY_SCOPE_AGENT);
  }
  if (blockIdx.x == 0) {
    if (threadIdx.x < 64) {
      int base = threadIdx.x * 4;
      for (;;) {
        bool done = true;
#pragma unroll
        for (int k = 0; k < 4; ++k) {
          int v = __hip_atomic_load(&flags[(base + k) * 16],
                                    __ATOMIC_RELAXED, __HIP_MEMORY_SCOPE_AGENT);
          done &= (v >= epoch);
        }
        if (done) break;
        __builtin_amdgcn_s_sleep(2);
      }
    }
    __syncthreads();
    if (threadIdx.x == 0) {
      __threadfence();
      __hip_atomic_store(gen, epoch, __ATOMIC_RELEASE, __HIP_MEMORY_SCOPE_AGENT);
    }
  } else {
    if (threadIdx.x == 0) {
      while (__hip_atomic_load(gen, __ATOMIC_RELAXED, __HIP_MEMORY_SCOPE_AGENT) < epoch) {
        __builtin_amdgcn_s_sleep(2);
      }
      __threadfence();
    }
  }
  __syncthreads();
}

// Grid-level (m,i)x3 + lse reduction over 256 block partials for batch bb.
// All 64 lanes of the calling wave end with the merged state (butterfly).
__device__ __forceinline__ void grid_reduce(
    int bb, int lane, bool need_tok,
    const float* __restrict__ pm0, const float* __restrict__ pm1,
    const float* __restrict__ pm2, const int* __restrict__ pi0,
    const int* __restrict__ pi1, const int* __restrict__ pi2,
    const float* __restrict__ ps, const float* __restrict__ hp,
    const float* __restrict__ Wlin, const float* __restrict__ blin,
    int* tk_sh, float* nm_sh) {
  float M0 = NEG_INF, M1 = NEG_INF, M2 = NEG_INF;
  int I0 = INT_MAX, I1 = INT_MAX, I2 = INT_MAX;
  float M = NEG_INF, S = 0.f;
  const int base = bb * NBLK;
#pragma unroll
  for (int r = 0; r < 4; ++r) {
    int wb = lane + r * 64;
    float a0 = pm0[base + wb], a1 = pm1[base + wb], a2 = pm2[base + wb];
    int   j0 = pi0[base + wb], j1 = pi1[base + wb], j2 = pi2[base + wb];
    float s  = ps[base + wb];
    ins3(M0, M1, M2, I0, I1, I2, a0, j0);
    ins3(M0, M1, M2, I0, I1, I2, a1, j1);
    ins3(M0, M1, M2, I0, I1, I2, a2, j2);
    lse_merge(M, S, a0, s);
  }
#pragma unroll
  for (int off = 32; off; off >>= 1) {
    float xm0 = __shfl_xor(M0, off, 64), xm1 = __shfl_xor(M1, off, 64);
    float xm2 = __shfl_xor(M2, off, 64), xs = __shfl_xor(S, off, 64);
    int xi0 = __shfl_xor(I0, off, 64), xi1 = __shfl_xor(I1, off, 64);
    int xi2 = __shfl_xor(I2, off, 64);
    lse_merge(M, S, xm0, xs);
    ins3(M0, M1, M2, I0, I1, I2, xm0, xi0);
    ins3(M0, M1, M2, I0, I1, I2, xm1, xi1);
    ins3(M0, M1, M2, I0, I1, I2, xm2, xi2);
  }
  float nm = M0 + logf(S);
  if (need_tok) {
    int tk = I0;
    if (M0 - M1 < THR) {   // fp16 decision ambiguous: fp32 recompute candidates
      const float* hpB = hp + bb * Hh;
      float vr[3]; int ir[3] = {I0, I1, I2};
#pragma unroll
      for (int r = 0; r < 3; ++r) {
        const v4f* w4 = reinterpret_cast<const v4f*>(Wlin + (size_t)ir[r] * Hh) + lane * 4;
        const v4f* h4 = reinterpret_cast<const v4f*>(hpB) + lane * 4;
        float a = 0.f;
#pragma unroll
        for (int k = 0; k < 4; ++k) a = dot4f(h4[k], w4[k], a);
#pragma unroll
        for (int off = 32; off; off >>= 1) a += __shfl_xor(a, off, 64);
        vr[r] = a + blin[ir[r]];
      }
      float vb = vr[0]; tk = ir[0];
#pragma unroll
      for (int r = 1; r < 3; ++r)
        if (vr[r] > vb || (vr[r] == vb && ir[r] < tk)) { vb = vr[r]; tk = ir[r]; }
    }
    if (lane == 0) tk_sh[bb] = tk;
  }
  if (lane == 0) nm_sh[bb] = nm;
}

__global__ void wconv_kernel(const float* __restrict__ w, _Float16* __restrict__ o, int n8) {
  int i = blockIdx.x * blockDim.x + threadIdx.x;
  int stride = gridDim.x * blockDim.x;
  for (; i < n8; i += stride) {
    const v4f* p = reinterpret_cast<const v4f*>(w + (size_t)i * 8);
    v4f a = p[0], b = p[1];
    h8v r;
    r[0] = (_Float16)a.x; r[1] = (_Float16)a.y; r[2] = (_Float16)a.z; r[3] = (_Float16)a.w;
    r[4] = (_Float16)b.x; r[5] = (_Float16)b.y; r[6] = (_Float16)b.z; r[7] = (_Float16)b.w;
    *reinterpret_cast<h8v*>(o + (size_t)i * 8) = r;
  }
}

template <int MODE>   // 1: fp16 W_lin via dot2; 0: fp32 fallback
__global__ void __launch_bounds__(NTHR, 4)
decoder_rnn_kernel(const float* __restrict__ enc_h,
                   const float* __restrict__ enc_c,
                   const float* __restrict__ emb,
                   const float* __restrict__ Wih,
                   const float* __restrict__ Whh,
                   const float* __restrict__ bih,
                   const float* __restrict__ bhh,
                   const float* __restrict__ Wlin,
                   const float* __restrict__ blin,
                   const _Float16* __restrict__ W16,
                   float* __restrict__ out,
                   int* flags, int* gen,
                   float* hb0, float* hb1, float* cbuf,
                   float* pm0, float* pm1, float* pm2,
                   int* pi0, int* pi1, int* pi2, float* ps)
{
  __shared__ float hbuf[Bb * P32];          // 65.8 KB; MODE1 aliases fp16 pitch P16
  __shared__ float gpart[WPB][8][Bb];       // 8 KB
  __shared__ float wpm[3][WPB][Bb];
  __shared__ int   wpi[3][WPB][Bb];
  __shared__ float wps[WPB][Bb];
  __shared__ int   tk_sh[Bb];
  __shared__ float nm_sh[Bb];

  const int tid  = threadIdx.x;
  const int lane = tid & 63;
  const int wid  = tid >> 6;                 // 0..15
  const int q    = lane >> 4;                // 0..3
  const int b    = lane & 15;
  const int bid  = blockIdx.x;
  const int wgl  = bid * WPB + wid;          // 0..4095; <4000 active in logits
  int ep = 0;
  _Float16* h16 = reinterpret_cast<_Float16*>(hbuf);

  float accL[2][4];
#pragma unroll
  for (int g = 0; g < 2; ++g)
#pragma unroll
    for (int r = 0; r < 4; ++r) accL[g][r] = 0.f;

  for (int t = 0; t < Tt; ++t) {
    float* hcur = (t & 1) ? hb1 : hb0;
    const float* hprev = (t == 0) ? enc_h : ((t & 1) ? hb0 : hb1);

    // ---------- phase A1: reduce step t-1 partials -> token + norm ----------
    if (t > 0) {
      grid_reduce(wid, lane, true, pm0, pm1, pm2, pi0, pi1, pi2, ps,
                  hprev, Wlin, blin, tk_sh, nm_sh);
    } else {
      if (tid < Bb) tk_sh[tid] = 1;          // SOS
    }
    __syncthreads();

    // ---------- A3: write normalized logits of step t-1 ----------
    if (t > 0 && wgl < 4000 && q == 0) {
      float nb = nm_sh[b];
      size_t obase = ((size_t)b * Tt + (t - 1)) * (size_t)Vv;
#pragma unroll
      for (int g = 0; g < 2; ++g) {
        int rbase = wgl * 8 + g * 4;
        v4f vo;
        vo.x = accL[g][0] - nb; vo.y = accL[g][1] - nb;
        vo.z = accL[g][2] - nb; vo.w = accL[g][3] - nb;
        __builtin_nontemporal_store(vo, reinterpret_cast<v4f*>(out + obase + rbase));
      }
    }

    // ---------- A4: gates (x, h read from global; hot in L2) ----------
    {
      const int jj = wid >> 2;               // 0..3 -> j column
      const int kq = wid & 3;                // K quarter
      const int j  = bid * 4 + jj;
      const int ko = kq * 256 + q * 64;      // float offset, 64 floats per lane
      const v4f* wi = reinterpret_cast<const v4f*>(Wih + (size_t)j * Hh + ko);
      const v4f* wh = reinterpret_cast<const v4f*>(Whh + (size_t)j * Hh + ko);
      const size_t gs = (size_t)Hh * Hh / 4; // v4f stride between gate sections
      const v4f* xv4 = reinterpret_cast<const v4f*>(emb + (size_t)tk_sh[b] * Hh + ko);
      const v4f* hv4 = reinterpret_cast<const v4f*>(hprev + (size_t)b * Hh + ko);
      float a0 = 0, a1 = 0, a2 = 0, a3 = 0, a4 = 0, a5 = 0, a6 = 0, a7 = 0;
#pragma unroll 4
      for (int i = 0; i < 16; ++i) {
        v4f xv = xv4[i];
        v4f hv = hv4[i];
        a0 = dot4f(xv, wi[i], a0);
        a1 = dot4f(xv, wi[i + gs], a1);
        a2 = dot4f(xv, wi[i + 2 * gs], a2);
        a3 = dot4f(xv, wi[i + 3 * gs], a3);
        a4 = dot4f(hv, wh[i], a4);
        a5 = dot4f(hv, wh[i + gs], a5);
        a6 = dot4f(hv, wh[i + 2 * gs], a6);
        a7 = dot4f(hv, wh[i + 3 * gs], a7);
      }
      a0 += __shfl_xor(a0, 16, 64); a0 += __shfl_xor(a0, 32, 64);
      a1 += __shfl_xor(a1, 16, 64); a1 += __shfl_xor(a1, 32, 64);
      a2 += __shfl_xor(a2, 16, 64); a2 += __shfl_xor(a2, 32, 64);
      a3 += __shfl_xor(a3, 16, 64); a3 += __shfl_xor(a3, 32, 64);
      a4 += __shfl_xor(a4, 16, 64); a4 += __shfl_xor(a4, 32, 64);
      a5 += __shfl_xor(a5, 16, 64); a5 += __shfl_xor(a5, 32, 64);
      a6 += __shfl_xor(a6, 16, 64); a6 += __shfl_xor(a6, 32, 64);
      a7 += __shfl_xor(a7, 16, 64); a7 += __shfl_xor(a7, 32, 64);
      if (q == 0) {
        gpart[wid][0][b] = a0; gpart[wid][1][b] = a1;
        gpart[wid][2][b] = a2; gpart[wid][3][b] = a3;
        gpart[wid][4][b] = a4; gpart[wid][5][b] = a5;
        gpart[wid][6][b] = a6; gpart[wid][7][b] = a7;
      }
    }
    __syncthreads();
    // ---------- A5: combine K-quarters + LSTM pointwise (wave 0) ----------
    if (wid == 0) {
      const int jj = q;
      const int j  = bid * 4 + jj;
      float sg[8];
#pragma unroll
      for (int g = 0; g < 8; ++g) {
        sg[g] = gpart[jj * 4 + 0][g][b] + gpart[jj * 4 + 1][g][b]
              + gpart[jj * 4 + 2][g][b] + gpart[jj * 4 + 3][g][b];
      }
      float gi = sg[0] + sg[4] + bih[j]          + bhh[j];
      float gf = sg[1] + sg[5] + bih[Hh + j]     + bhh[Hh + j];
      float gg = sg[2] + sg[6] + bih[2 * Hh + j] + bhh[2 * Hh + j];
      float go = sg[3] + sg[7] + bih[3 * Hh + j] + bhh[3 * Hh + j];
      float cold = (t == 0) ? enc_c[b * Hh + j] : cbuf[b * Hh + j];
      float ig = 1.f / (1.f + expf(-gi));
      float fg = 1.f / (1.f + expf(-gf));
      float og = 1.f / (1.f + expf(-go));
      float cn = fg * cold + ig * tanhf(gg);
      float hn = og * tanhf(cn);
      cbuf[b * Hh + j] = cn;
      hcur[b * Hh + j] = hn;
    }
    grid_barrier(flags, gen, ++ep);

    // ---------- phase B: logits ----------
    {   // stage h into LDS (fp16 in MODE1, fp32 in MODE0)
      int row = tid >> 6;
      int col = (tid & 63) * 16;
      const v4f* src = reinterpret_cast<const v4f*>(hcur + (size_t)row * Hh + col);
      v4f v0 = src[0], v1 = src[1], v2 = src[2], v3 = src[3];
      if (MODE == 1) {
        h8v r0, r1;
        r0[0]=(_Float16)v0.x; r0[1]=(_Float16)v0.y; r0[2]=(_Float16)v0.z; r0[3]=(_Float16)v0.w;
        r0[4]=(_Float16)v1.x; r0[5]=(_Float16)v1.y; r0[6]=(_Float16)v1.z; r0[7]=(_Float16)v1.w;
        r1[0]=(_Float16)v2.x; r1[1]=(_Float16)v2.y; r1[2]=(_Float16)v2.z; r1[3]=(_Float16)v2.w;
        r1[4]=(_Float16)v3.x; r1[5]=(_Float16)v3.y; r1[6]=(_Float16)v3.z; r1[7]=(_Float16)v3.w;
        *reinterpret_cast<h8v*>(h16 + row * P16 + col) = r0;
        *reinterpret_cast<h8v*>(h16 + row * P16 + col + 8) = r1;
      } else {
        v4f* dst = reinterpret_cast<v4f*>(hbuf + row * P32 + col);
        dst[0] = v0; dst[1] = v1; dst[2] = v2; dst[3] = v3;
      }
    }
    __syncthreads();

    float m0 = NEG_INF, m1 = NEG_INF, m2 = NEG_INF;
    int i0 = INT_MAX, i1 = INT_MAX, i2 = INT_MAX;
    float sl = 0.f;
    if (wgl < 4000) {
#pragma unroll
      for (int g = 0; g < 2; ++g) {
        size_t rbase = (size_t)wgl * 8 + g * 4;
        float a0 = 0, a1 = 0, a2 = 0, a3 = 0;
        if (MODE == 1) {
          const _Float16* hbp = h16 + b * P16 + q * 256;
          const _Float16* wr = W16 + rbase * Hh + q * 256;
#pragma unroll 4
          for (int i = 0; i < 32; ++i) {
            h8v hh = *reinterpret_cast<const h8v*>(hbp + i * 8);
            a0 = dot8h(hh, *reinterpret_cast<const h8v*>(wr + i * 8), a0);
            a1 = dot8h(hh, *reinterpret_cast<const h8v*>(wr + Hh + i * 8), a1);
            a2 = dot8h(hh, *reinterpret_cast<const h8v*>(wr + 2 * Hh + i * 8), a2);
            a3 = dot8h(hh, *reinterpret_cast<const h8v*>(wr + 3 * Hh + i * 8), a3);
          }
        } else {
          const float* hbp = hbuf + b * P32 + q * 256;
          const v4f* w0 = reinterpret_cast<const v4f*>(Wlin + rbase * Hh) + q * 64;
          const v4f* w1 = w0 + 256;
          const v4f* w2 = w1 + 256;
          const v4f* w3 = w2 + 256;
#pragma unroll 4
          for (int i = 0; i < 64; ++i) {
            v4f hv = *reinterpret_cast<const v4f*>(hbp + i * 4);
            a0 = dot4f(hv, w0[i], a0);
            a1 = dot4f(hv, w1[i], a1);
            a2 = dot4f(hv, w2[i], a2);
            a3 = dot4f(hv, w3[i], a3);
          }
        }
        a0 += __shfl_xor(a0, 16, 64); a0 += __shfl_xor(a0, 32, 64);
        a1 += __shfl_xor(a1, 16, 64); a1 += __shfl_xor(a1, 32, 64);
        a2 += __shfl_xor(a2, 16, 64); a2 += __shfl_xor(a2, 32, 64);
        a3 += __shfl_xor(a3, 16, 64); a3 += __shfl_xor(a3, 32, 64);
        int rb0 = (int)rbase;
        a0 += blin[rb0]; a1 += blin[rb0 + 1]; a2 += blin[rb0 + 2]; a3 += blin[rb0 + 3];
        accL[g][0] = a0; accL[g][1] = a1; accL[g][2] = a2; accL[g][3] = a3;
        ins3(m0, m1, m2, i0, i1, i2, a0, rb0);
        ins3(m0, m1, m2, i0, i1, i2, a1, rb0 + 1);
        ins3(m0, m1, m2, i0, i1, i2, a2, rb0 + 2);
        ins3(m0, m1, m2, i0, i1, i2, a3, rb0 + 3);
      }
#pragma unroll
      for (int g = 0; g < 2; ++g)
#pragma unroll
        for (int r = 0; r < 4; ++r) sl += __expf(accL[g][r] - m0);
    }
    if (q == 0) {
      wpm[0][wid][b] = m0; wpm[1][wid][b] = m1; wpm[2][wid][b] = m2;
      wpi[0][wid][b] = i0; wpi[1][wid][b] = i1; wpi[2][wid][b] = i2;
      wps[wid][b] = sl;
    }
    __syncthreads();
    if (tid < Bb) {        // block-level merge: 16 waves -> 1 partial per batch
      const int bb = tid;
      float M0 = NEG_INF, M1 = NEG_INF, M2 = NEG_INF;
      int I0 = INT_MAX, I1 = INT_MAX, I2 = INT_MAX;
      float M = NEG_INF, S = 0.f;
#pragma unroll
      for (int w = 0; w < WPB; ++w) {
        float a0 = wpm[0][w][bb], a1 = wpm[1][w][bb], a2 = wpm[2][w][bb];
        lse_merge(M, S, a0, wps[w][bb]);
        ins3(M0, M1, M2, I0, I1, I2, a0, wpi[0][w][bb]);
        ins3(M0, M1, M2, I0, I1, I2, a1, wpi[1][w][bb]);
        ins3(M0, M1, M2, I0, I1, I2, a2, wpi[2][w][bb]);
      }
      pm0[bb * NBLK + bid] = M0; pm1[bb * NBLK + bid] = M1; pm2[bb * NBLK + bid] = M2;
      pi0[bb * NBLK + bid] = I0; pi1[bb * NBLK + bid] = I1; pi2[bb * NBLK + bid] = I2;
      ps[bb * NBLK + bid] = S;
    }
    grid_barrier(flags, gen, ++ep);
  }

  // ===== tail: norm for t=127, final logits, h, c =====
  grid_reduce(wid, lane, false, pm0, pm1, pm2, pi0, pi1, pi2, ps,
              hb1, Wlin, blin, tk_sh, nm_sh);
  __syncthreads();
  if (wgl < 4000 && q == 0) {
    float nb = nm_sh[b];
    size_t obase = ((size_t)b * Tt + (Tt - 1)) * (size_t)Vv;
#pragma unroll
    for (int g = 0; g < 2; ++g) {
      int rbase = wgl * 8 + g * 4;
      v4f vo;
      vo.x = accL[g][0] - nb; vo.y = accL[g][1] - nb;
      vo.z = accL[g][2] - nb; vo.w = accL[g][3] - nb;
      __builtin_nontemporal_store(vo, reinterpret_cast<v4f*>(out + obase + rbase));
    }
  }
  size_t tail = (size_t)Bb * Tt * Vv;
  for (int i = bid * NTHR + tid; i < Bb * Hh; i += NBLK * NTHR) {
    out[tail + i] = hb1[i];
    out[tail + Bb * Hh + i] = cbuf[i];
  }
}

extern "C" void kernel_launch(void* const* d_in, const int* in_sizes, int n_in,
                              void* d_out, int out_size, void* d_ws, size_t ws_size,
                              hipStream_t stream) {
  const float* enc_h = (const float*)d_in[1];
  const float* enc_c = (const float*)d_in[2];
  const float* emb   = (const float*)d_in[3];
  const float* Wih   = (const float*)d_in[4];
  const float* Whh   = (const float*)d_in[5];
  const float* bih   = (const float*)d_in[6];
  const float* bhh   = (const float*)d_in[7];
  const float* Wlin  = (const float*)d_in[8];
  const float* blin  = (const float*)d_in[9];
  float* out = (float*)d_out;

  char* ws = (char*)d_ws;
  int*   flags = (int*)ws;                        // 16 KB (256 x 64B)
  int*   gen   = (int*)(ws + 16384);
  float* hb0   = (float*)(ws + 17408);
  float* hb1   = (float*)(ws + 82944);
  float* cbuf  = (float*)(ws + 148480);
  float* pm0   = (float*)(ws + 214016);           // [16][256]
  float* pm1   = (float*)(ws + 230400);
  float* pm2   = (float*)(ws + 246784);
  int*   pi0   = (int*)  (ws + 263168);
  int*   pi1   = (int*)  (ws + 279552);
  int*   pi2   = (int*)  (ws + 295936);
  float* ps    = (float*)(ws + 312320);
  _Float16* W16 = (_Float16*)(ws + 328704);       // 65,536,000 B
  const size_t need16 = 328704ULL + 65536000ULL;

  hipMemsetAsync(d_ws, 0, 16448, stream);         // zero barrier state

  bool use16 = (ws_size >= need16);
  if (use16) {
    wconv_kernel<<<dim3(4096), dim3(512), 0, stream>>>(Wlin, W16, 4096000);
    auto* fp = decoder_rnn_kernel<1>;
    void* kargs[] = { (void*)&enc_h, (void*)&enc_c, (void*)&emb, (void*)&Wih,
                      (void*)&Whh, (void*)&bih, (void*)&bhh, (void*)&Wlin,
                      (void*)&blin, (void*)&W16, (void*)&out, (void*)&flags,
                      (void*)&gen, (void*)&hb0, (void*)&hb1, (void*)&cbuf,
                      (void*)&pm0, (void*)&pm1, (void*)&pm2,
                      (void*)&pi0, (void*)&pi1, (void*)&pi2, (void*)&ps };
    hipError_t e = hipLaunchCooperativeKernel((const void*)fp, dim3(NBLK),
                                              dim3(NTHR), kargs, 0, stream);
    if (e != hipSuccess) {
      decoder_rnn_kernel<1><<<dim3(NBLK), dim3(NTHR), 0, stream>>>(
          enc_h, enc_c, emb, Wih, Whh, bih, bhh, Wlin, blin, W16, out,
          flags, gen, hb0, hb1, cbuf, pm0, pm1, pm2, pi0, pi1, pi2, ps);
    }
  } else {
    auto* fp = decoder_rnn_kernel<0>;
    void* kargs[] = { (void*)&enc_h, (void*)&enc_c, (void*)&emb, (void*)&Wih,
                      (void*)&Whh, (void*)&bih, (void*)&bhh, (void*)&Wlin,
                      (void*)&blin, (void*)&W16, (void*)&out, (void*)&flags,
                      (void*)&gen, (void*)&hb0, (void*)&hb1, (void*)&cbuf,
                      (void*)&pm0, (void*)&pm1, (void*)&pm2,
                      (void*)&pi0, (void*)&pi1, (void*)&pi2, (void*)&ps };
    hipError_t e = hipLaunchCooperativeKernel((const void*)fp, dim3(NBLK),
                                              dim3(NTHR), kargs, 0, stream);
    if (e != hipSuccess) {
      decoder_rnn_kernel<0><<<dim3(NBLK), dim3(NTHR), 0, stream>>>(
          enc_h, enc_c, emb, Wih, Whh, bih, bhh, Wlin, blin, W16, out,
          flags, gen, hb0, hb1, cbuf, pm0, pm1, pm2, pi0, pi1, pi2, ps);
    }
  }
}